// Round 4
// baseline (531.301 us; speedup 1.0000x reference)
//
#include <hip/hip_runtime.h>
#include <stdint.h>

// ---------------------------------------------------------------------------
// SimVQ: z_e (8192x512 f32), codebook (16384x512 f32), W (512x512 f32)
// eff = codebook @ W.T; idx[i] = argmin_k (||eff_k||^2 - 2 z_i.eff_k)
// z_q = eff[idx]; total_loss = 1.25 * mean((z_e - z_q)^2)
// out (f32): [z_q (4194304)] [loss (1)] [indices-as-float (8192)]
//
// eff GEMM: 3-limb f16 MFMA, 128^2 tiles; epilogue writes fp32 eff AND the
// pre-tiled 1-limb f16 BpT for the dist pass.
// dist1 v4: 32x32x16 f16 MFMA (256 instr/block-K-step instead of 512),
// k16-outermost ordering (8 independent accumulators per window, chain
// distance 8), r0 staging/vmcnt discipline (counted VMCNT(6), drain at t=6).
// Pre-tiled [kblk][row][8] layout serves 32x32 fragments unchanged.
// Epilogue: 32x32 C layout, per-32col-group minima + candidate-col ballots.
// Refine: exact fp32 on masked cols only (2 KB/col).
// ---------------------------------------------------------------------------

#define N_ROWS 8192
#define DIM    512
#define K_CB   16384
#define TILE_F16 16384         // 256x64 f16 (32 KB)
#define HALF_F16 8192
#define KT_EFF 24              // eff GEMM: K'=1536
#define KT_D   8               // dist pass: K=512
#define PAN_D   ((size_t)KT_D * TILE_F16)
#define RMARGIN 4.0f

typedef _Float16 f16x8 __attribute__((ext_vector_type(8)));
typedef float f32x4 __attribute__((ext_vector_type(4)));
typedef float f32x16 __attribute__((ext_vector_type(16)));

#define FENCE() asm volatile("" ::: "memory")
#define BARRIER() do { FENCE(); __builtin_amdgcn_s_barrier(); FENCE(); } while (0)
#define VMCNT(n) asm volatile("s_waitcnt vmcnt(" #n ")" ::: "memory")

__device__ __forceinline__ void gload_lds16(const void* g, void* l) {
  __builtin_amdgcn_global_load_lds(
      (const __attribute__((address_space(1))) uint32_t*)g,
      (__attribute__((address_space(3))) uint32_t*)l, 16, 0, 0);
}

// ----------------------- shared staging building block ---------------------

__device__ __forceinline__ void stage_half(const _Float16* src, _Float16* ldsb,
                                           int w, int lane) {
  const _Float16* s = src + w * 512 + lane * 8;
  _Float16* l = ldsb + w * 512;
  gload_lds16(s, l);
  gload_lds16(s + 4096, l + 4096);
}

// -------------------- limb splits into pre-tiled layout --------------------
// 3-limb: [panel][kt(24)][half][kblk(8)][row(128)][8]; limb group per kt/8.
__global__ __launch_bounds__(256) void split_tiled_kernel(
    const float* __restrict__ S, _Float16* __restrict__ T, int resid_limb) {
  const int b = blockIdx.x;
  const int mp = b / 48;
  const int r1 = b % 48;
  const int kt = r1 >> 1, half = r1 & 1;
  const int limb = kt >> 3;
  const int ksrc = (kt & 7) * 64;
  const bool resid = (limb == resid_limb);
  const int t = threadIdx.x;
  _Float16* dst = T + ((size_t)(mp * KT_EFF + kt) * 2 + half) * HALF_F16;
#pragma unroll
  for (int cc = 0; cc < 4; ++cc) {
    const int ci = cc * 256 + t;
    const int kblk = ci >> 7, row = ci & 127;
    const int m = mp * 256 + half * 128 + row;
    const float* src = &S[(size_t)m * DIM + ksrc + kblk * 8];
    float4 x0 = *reinterpret_cast<const float4*>(src);
    float4 x1 = *reinterpret_cast<const float4*>(src + 4);
    const float xs[8] = {x0.x, x0.y, x0.z, x0.w, x1.x, x1.y, x1.z, x1.w};
    f16x8 o;
    if (!resid) {
#pragma unroll
      for (int j = 0; j < 8; ++j) o[j] = (_Float16)xs[j];
    } else {
#pragma unroll
      for (int j = 0; j < 8; ++j) {
        _Float16 h = (_Float16)xs[j];
        o[j] = (_Float16)(xs[j] - (float)h);
      }
    }
    *reinterpret_cast<f16x8*>(&dst[(size_t)ci * 8]) = o;
  }
}

// 1-limb: [panel][kt(8)][half][kblk(8)][row(128)][8]  (for z_e -> ApT)
__global__ __launch_bounds__(256) void split1_kernel(
    const float* __restrict__ S, _Float16* __restrict__ T) {
  const int b = blockIdx.x;
  const int p = b >> 4;
  const int r1 = b & 15;
  const int kt = r1 >> 1, half = r1 & 1;
  const int ksrc = kt * 64;
  const int t = threadIdx.x;
  _Float16* dst = T + ((size_t)(p * KT_D + kt) * 2 + half) * HALF_F16;
#pragma unroll
  for (int cc = 0; cc < 4; ++cc) {
    const int ci = cc * 256 + t;
    const int kblk = ci >> 7, row = ci & 127;
    const int m = p * 256 + half * 128 + row;
    const float* src = &S[(size_t)m * DIM + ksrc + kblk * 8];
    float4 x0 = *reinterpret_cast<const float4*>(src);
    float4 x1 = *reinterpret_cast<const float4*>(src + 4);
    const float xs[8] = {x0.x, x0.y, x0.z, x0.w, x1.x, x1.y, x1.z, x1.w};
    f16x8 o;
#pragma unroll
    for (int j = 0; j < 8; ++j) o[j] = (_Float16)xs[j];
    *reinterpret_cast<f16x8*>(&dst[(size_t)ci * 8]) = o;
  }
}

// ----------------- eff GEMM: 128^2 tiles, fused f16 emission ---------------
// Block: 256 thr, 4 waves (2x2 of 64x64), BK=64, double-buffered 64 KB LDS.
// Epilogue writes fp32 eff AND pre-tiled 1-limb BpT.
__global__ __launch_bounds__(256) void effgemm128_kernel(
    const _Float16* __restrict__ CpT, const _Float16* __restrict__ WpT,
    float* __restrict__ eff, _Float16* __restrict__ BpT) {
  __shared__ __align__(16) _Float16 lbuf[2][2][HALF_F16];  // 64 KB
  const int tid = threadIdx.x;
  const int w = tid >> 6, lane = tid & 63;
  const int lh = lane & 15, lq = lane >> 4;
  const int wr = w >> 1, wc = w & 1;
  const int bid = blockIdx.x;
  const int nb = bid & 3, mh = bid >> 2;       // mh: 128-row half (0..127)
  const int pA = mh >> 1, hA = mh & 1;
  const int pB = nb >> 1, hB = nb & 1;
  f32x4 acc[4][4] = {};

  // stage one kt (A-half + B-half) into buf
  auto stage = [&](int kt, int buf) {
    const _Float16* a = CpT + (((size_t)pA * KT_EFF + kt) * 2 + hA) * HALF_F16;
    const _Float16* b = WpT + (((size_t)pB * KT_EFF + kt) * 2 + hB) * HALF_F16;
#pragma unroll
    for (int i = 0; i < 4; ++i) {
      const int off = i * 2048 + w * 512;
      gload_lds16(a + off + lane * 8, &lbuf[buf][0][off]);
      gload_lds16(b + off + lane * 8, &lbuf[buf][1][off]);
    }
  };

  stage(0, 0);
  for (int kt = 0; kt < KT_EFF; ++kt) {
    __syncthreads();
    if (kt + 1 < KT_EFF) stage(kt + 1, (kt + 1) & 1);
    const _Float16* At = &lbuf[kt & 1][0][0];
    const _Float16* Bt = &lbuf[kt & 1][1][0];
    f16x8 af[4][2], bf[4][2];
#pragma unroll
    for (int mf = 0; mf < 4; ++mf) {
      const int r = wr * 64 + mf * 16 + lh;
#pragma unroll
      for (int kk = 0; kk < 2; ++kk)
        af[mf][kk] = *reinterpret_cast<const f16x8*>(
            &At[((kk * 4 + lq) * 128 + r) * 8]);
    }
#pragma unroll
    for (int nf = 0; nf < 4; ++nf) {
      const int r = wc * 64 + nf * 16 + lh;
#pragma unroll
      for (int kk = 0; kk < 2; ++kk)
        bf[nf][kk] = *reinterpret_cast<const f16x8*>(
            &Bt[((kk * 4 + lq) * 128 + r) * 8]);
    }
    __builtin_amdgcn_s_setprio(1);
#pragma unroll
    for (int mf = 0; mf < 4; ++mf)
#pragma unroll
      for (int nf = 0; nf < 4; ++nf)
#pragma unroll
        for (int kk = 0; kk < 2; ++kk)
          acc[mf][nf] = __builtin_amdgcn_mfma_f32_16x16x32_f16(
              af[mf][kk], bf[nf][kk], acc[mf][nf], 0, 0, 0);
    __builtin_amdgcn_s_setprio(0);
  }

#pragma unroll
  for (int mf = 0; mf < 4; ++mf)
#pragma unroll
    for (int nf = 0; nf < 4; ++nf)
#pragma unroll
      for (int j = 0; j < 4; ++j) {
        const int rl = wr * 64 + mf * 16 + lq * 4 + j;
        const int cl = wc * 64 + nf * 16 + lh;
        const int row = mh * 128 + rl;
        const int col = nb * 128 + cl;
        const float v = acc[mf][nf][j];
        eff[(size_t)row * DIM + col] = v;
        const int ktd = col >> 6, kblk = (col >> 3) & 7, ce = col & 7;
        BpT[((((size_t)(row >> 8) * KT_D + ktd) * 2 + ((row >> 7) & 1)) * 8 + kblk)
                * 1024 + (row & 127) * 8 + ce] = (_Float16)v;
      }
}

__global__ __launch_bounds__(256) void effnorm_kernel(
    const float* __restrict__ E, float* __restrict__ En) {
  const int w = threadIdx.x >> 6;
  const int lane = threadIdx.x & 63;
  const int row = blockIdx.x * 4 + w;
  const float* er = &E[(size_t)row * DIM];
  float s = 0.f;
#pragma unroll
  for (int k = 0; k < DIM / 64; ++k) {
    float v = er[lane + k * 64];
    s = fmaf(v, v, s);
  }
#pragma unroll
  for (int o = 32; o; o >>= 1) s += __shfl_down(s, o, 64);
  if (lane == 0) En[row] = s;
}

// ------------------ dist pass 1 v4: 32x32x16 f16 MFMA ----------------------
// Grid 2048, XCD supertile map (round-0). Block: 512 thr, 8 waves (2x4 of
// 128x64). Per K-step: stage A(t+1)h2 early; 24 ds_read_b128 (A 16, B 8);
// mid-barrier; 32 MFMA k16-outer (8 independent acc per window); stage
// B(t+2)+A(t+2) post-MFMA; counted VMCNT(6) (drain-0 at t=6); barrier.
// A frag (lane l): row = base + (l&31), k = (l>>5)*8+j  -> kblk = k16*2+(l>>5)
// C frag: col = lane&31, row = (reg&3) + 8*(reg>>2) + 4*(lane>>5).
__global__ __launch_bounds__(512) void dist1_kernel(
    const _Float16* __restrict__ ApT, const _Float16* __restrict__ BpT,
    const float* __restrict__ En, float* __restrict__ gv,
    unsigned* __restrict__ gmask) {
  __shared__ __align__(16) _Float16 lds[4][TILE_F16];
  const int tid = threadIdx.x;
  const int w = tid >> 6, lane = tid & 63;
  const int l31 = lane & 31, kh = lane >> 5;
  const int wr = w >> 2, wc = w & 3;
  const int bid = blockIdx.x;
  const int xcd = bid & 7, c = bid >> 3;
  const int np = xcd * 8 + (c & 7);
  const int mp = c >> 3;
  const _Float16* Ab = ApT + (size_t)mp * PAN_D;
  const _Float16* Bb = BpT + (size_t)np * PAN_D;

  float en[2];
  en[0] = En[np * 256 + wc * 64 + l31];
  en[1] = En[np * 256 + wc * 64 + 32 + l31];

  f32x16 acc[4][2] = {};
  f16x8 a32[4][4], b32[2][4];

  // prologue: tiles 0 and 1 (r0 order): A0h1 A0h2 B0h1 B0h2 B1h1 B1h2 A1h1
  stage_half(Ab, &lds[0][0], w, lane);
  stage_half(Ab + HALF_F16, &lds[0][HALF_F16], w, lane);
  stage_half(Bb, &lds[1][0], w, lane);
  stage_half(Bb + HALF_F16, &lds[1][HALF_F16], w, lane);
  stage_half(Bb + TILE_F16, &lds[3][0], w, lane);
  stage_half(Bb + TILE_F16 + HALF_F16, &lds[3][HALF_F16], w, lane);
  stage_half(Ab + TILE_F16, &lds[2][0], w, lane);
  VMCNT(6);                      // tile 0 resident; 6 in flight (tile 1)
  BARRIER();

  for (int t = 0; t < KT_D; ++t) {
    const int s = t & 1;
    const _Float16* At = &lds[s * 2 + 0][0];
    const _Float16* Bt = &lds[s * 2 + 1][0];
    // earliest-issue: finish tile t+1's A (its buffer was consumed at t-1)
    if (t + 1 < KT_D)
      stage_half(Ab + (size_t)(t + 1) * TILE_F16 + HALF_F16,
                 &lds[(s ^ 1) * 2][HALF_F16], w, lane);
    // fragment reads: A 16, B 8 (conflict-free: quarter-waves contiguous)
#pragma unroll
    for (int mi = 0; mi < 4; ++mi)
#pragma unroll
      for (int k16 = 0; k16 < 4; ++k16)
        a32[mi][k16] = *reinterpret_cast<const f16x8*>(
            &At[(((wr * 8 + k16 * 2 + kh) * 128) + mi * 32 + l31) * 8]);
    {
      const int halfb = wc >> 1, rb = (wc & 1) * 64 + l31;
#pragma unroll
      for (int ni = 0; ni < 2; ++ni)
#pragma unroll
        for (int k16 = 0; k16 < 4; ++k16)
          b32[ni][k16] = *reinterpret_cast<const f16x8*>(
              &Bt[(((halfb * 8 + k16 * 2 + kh) * 128) + rb + ni * 32) * 8]);
    }
    BARRIER();  // every wave has ISSUED its reads of bufs s before overwrites
    __builtin_amdgcn_s_setprio(1);
#pragma unroll
    for (int k16 = 0; k16 < 4; ++k16)
#pragma unroll
      for (int mi = 0; mi < 4; ++mi)
#pragma unroll
        for (int ni = 0; ni < 2; ++ni)
          acc[mi][ni] = __builtin_amdgcn_mfma_f32_32x32x16_f16(
              a32[mi][k16], b32[ni][k16], acc[mi][ni], 0, 0, 0);
    __builtin_amdgcn_s_setprio(0);
    // post-MFMA staging of tile t+2 (B into the buffer read THIS step --
    // safe: >=620cyc MFMA + write latency after the mid-barrier read-issue)
    if (t + 2 < KT_D) {
      stage_half(Bb + (size_t)(t + 2) * TILE_F16, &lds[s * 2 + 1][0], w, lane);
      stage_half(Bb + (size_t)(t + 2) * TILE_F16 + HALF_F16,
                 &lds[s * 2 + 1][HALF_F16], w, lane);
      stage_half(Ab + (size_t)(t + 2) * TILE_F16, &lds[s * 2][0], w, lane);
    }
    if (t == KT_D - 2) { VMCNT(0); BARRIER(); }
    else if (t + 1 < KT_D) { VMCNT(6); BARRIER(); }
  }

  // epilogue: fold En, per-32col-group minima + candidate-col ballots.
  // Lanes 0-31 hold rows (reg&3)+8*(reg>>2), lanes 32-63 those +4; each
  // half's 32 lanes span exactly one 32-col group.
#pragma unroll
  for (int mi = 0; mi < 4; ++mi)
#pragma unroll
    for (int ni = 0; ni < 2; ++ni) {
#pragma unroll
      for (int reg = 0; reg < 16; ++reg) {
        const float sc = fmaf(-2.f, acc[mi][ni][reg], en[ni]);
        float g = sc;
#pragma unroll
        for (int m = 1; m < 32; m <<= 1) g = fminf(g, __shfl_xor(g, m, 64));
        const unsigned long long b = __ballot(sc <= g + RMARGIN);
        if (l31 == 0) {
          const int row = mp * 256 + wr * 128 + mi * 32 +
                          (reg & 3) + 8 * (reg >> 2) + 4 * kh;
          const int gidx = np * 8 + wc * 2 + ni;
          gv[(size_t)row * 512 + gidx] = g;
          gmask[(size_t)row * 512 + gidx] = (unsigned)(b >> (kh * 32));
        }
      }
    }
}

// ------------------------------- flag pass ---------------------------------
__global__ __launch_bounds__(256) void flag_kernel(
    const float* __restrict__ gv, int* __restrict__ fcnt,
    unsigned short* __restrict__ flist) {
  const int t = threadIdx.x;
  const int w = t >> 6, lane = t & 63;
  const int row = blockIdx.x * 4 + w;
  float v[8];
#pragma unroll
  for (int i = 0; i < 8; ++i) v[i] = gv[(size_t)row * 512 + i * 64 + lane];
  float A = v[0];
#pragma unroll
  for (int i = 1; i < 8; ++i) A = fminf(A, v[i]);
#pragma unroll
  for (int m = 1; m < 64; m <<= 1) A = fminf(A, __shfl_xor(A, m, 64));
  __shared__ int cnt[4];
  __shared__ unsigned short lst[4][64];
  if (lane == 0) cnt[w] = 0;
  __syncthreads();
  const float thr = A + RMARGIN;
#pragma unroll
  for (int i = 0; i < 8; ++i) {
    if (v[i] <= thr) {
      int p = atomicAdd(&cnt[w], 1);
      if (p < 64) lst[w][p] = (unsigned short)(i * 64 + lane);
    }
  }
  __syncthreads();
  const int cn = cnt[w];
  if (lane == 0) fcnt[row] = (cn > 64) ? -1 : cn;
  if (lane < cn && lane < 64) flist[(size_t)row * 64 + lane] = lst[w][lane];
}

// ------- refine v2: masked cols only, wave-per-group, no in-loop sync ------
__global__ __launch_bounds__(256) void refine_kernel(
    const float* __restrict__ Z, const float* __restrict__ E,
    const float* __restrict__ En, const int* __restrict__ fcnt,
    const unsigned short* __restrict__ flist, const unsigned* __restrict__ gmask,
    float* __restrict__ zq, float* __restrict__ out_idx,
    float* __restrict__ ploss) {
  const int row = blockIdx.x;
  const int t = threadIdx.x;
  const int w = t >> 6, lane = t & 63;
  const int hl = lane & 31;
  const int hi = lane >> 5;
  __shared__ float zrow[512];
  __shared__ unsigned short glist[512];
  __shared__ float bvs[4];
  __shared__ int bis[4];
  __shared__ int sidx;
  __shared__ float wsum[4];
  if (t < 128)
    ((float4*)zrow)[t] = ((const float4*)(Z + (size_t)row * 512))[t];
  const int cr = fcnt[row];
  int ng;
  if (cr < 0) {
    glist[t] = (unsigned short)t;
    glist[t + 256] = (unsigned short)(t + 256);
    ng = 512;
  } else {
    ng = cr;
    if (t < cr) glist[t] = flist[(size_t)row * 64 + t];
  }
  // per-lane z chunk: dims hl*16 .. hl*16+15 (same for both halves)
  float4 zr0, zr1, zr2, zr3;
  {
    const float4* zp = (const float4*)(Z + (size_t)row * 512 + hl * 16);
    zr0 = zp[0]; zr1 = zp[1]; zr2 = zp[2]; zr3 = zp[3];
  }
  __syncthreads();

  float bv = 3.0e38f;
  int bi = 2147483647;
  for (int q = w; q < ng; q += 4) {
    const int g = glist[q];
    unsigned m = gmask[(size_t)row * 512 + g];
    while (m) {
      const int c0 = __builtin_ctz(m);
      m &= m - 1;
      int c1 = -1;
      if (m) { c1 = __builtin_ctz(m); m &= m - 1; }
      const int cl = hi ? c1 : c0;
      const bool act = (cl >= 0);
      const int col = g * 32 + (act ? cl : c0);
      const float4* er = (const float4*)(E + (size_t)col * 512 + hl * 16);
      const float4 e0 = er[0], e1 = er[1], e2 = er[2], e3 = er[3];
      float p = 0.f;
      p = fmaf(zr0.x, e0.x, p); p = fmaf(zr0.y, e0.y, p);
      p = fmaf(zr0.z, e0.z, p); p = fmaf(zr0.w, e0.w, p);
      p = fmaf(zr1.x, e1.x, p); p = fmaf(zr1.y, e1.y, p);
      p = fmaf(zr1.z, e1.z, p); p = fmaf(zr1.w, e1.w, p);
      p = fmaf(zr2.x, e2.x, p); p = fmaf(zr2.y, e2.y, p);
      p = fmaf(zr2.z, e2.z, p); p = fmaf(zr2.w, e2.w, p);
      p = fmaf(zr3.x, e3.x, p); p = fmaf(zr3.y, e3.y, p);
      p = fmaf(zr3.z, e3.z, p); p = fmaf(zr3.w, e3.w, p);
#pragma unroll
      for (int s2 = 1; s2 < 32; s2 <<= 1) p += __shfl_xor(p, s2, 64);
      const float v = fmaf(-2.f, p, En[col]);
      if (act && (v < bv || (v == bv && col < bi))) { bv = v; bi = col; }
    }
  }
#pragma unroll
  for (int s2 = 1; s2 < 64; s2 <<= 1) {
    const float v2 = __shfl_xor(bv, s2, 64);
    const int i2 = __shfl_xor(bi, s2, 64);
    if (v2 < bv || (v2 == bv && i2 < bi)) { bv = v2; bi = i2; }
  }
  if (lane == 0) { bvs[w] = bv; bis[w] = bi; }
  __syncthreads();
  if (t == 0) {
    float fb = bvs[0];
    int fi = bis[0];
#pragma unroll
    for (int i = 1; i < 4; ++i)
      if (bvs[i] < fb || (bvs[i] == fb && bis[i] < fi)) { fb = bvs[i]; fi = bis[i]; }
    sidx = fi;
  }
  __syncthreads();
  const int idx = sidx;

  float s = 0.f;
  const float* erow = E + (size_t)idx * 512;
#pragma unroll
  for (int d0 = 0; d0 < 512; d0 += 256) {
    const int d = d0 + t;
    const float e = erow[d];
    const float z = zrow[d];
    zq[(size_t)row * 512 + d] = e;
    const float df = z - e;
    s = fmaf(df, df, s);
  }
#pragma unroll
  for (int o = 32; o; o >>= 1) s += __shfl_down(s, o, 64);
  if ((t & 63) == 0) wsum[t >> 6] = s;
  __syncthreads();
  if (t == 0) {
    ploss[row] = wsum[0] + wsum[1] + wsum[2] + wsum[3];
    out_idx[row] = (float)idx;
  }
}

__global__ __launch_bounds__(256) void loss_final_kernel(
    const float* __restrict__ ploss, float* __restrict__ out_loss) {
  const int t = threadIdx.x;
  double s = 0.0;
  for (int i = t; i < N_ROWS; i += 256) s += (double)ploss[i];
#pragma unroll
  for (int o = 32; o; o >>= 1) s += __shfl_down(s, o, 64);
  __shared__ double ds[4];
  if ((t & 63) == 0) ds[t >> 6] = s;
  __syncthreads();
  if (t == 0) {
    double tot = ds[0] + ds[1] + ds[2] + ds[3];
    out_loss[0] = (float)(1.25 * tot / ((double)N_ROWS * (double)DIM));
  }
}

// --------------------------------- launch ----------------------------------

extern "C" void kernel_launch(void* const* d_in, const int* in_sizes, int n_in,
                              void* d_out, int out_size, void* d_ws, size_t ws_size,
                              hipStream_t stream) {
  const float* z_e      = (const float*)d_in[0];
  const float* codebook = (const float*)d_in[1];
  const float* W        = (const float*)d_in[2];
  float* out = (float*)d_out;
  char* ws = (char*)d_ws;

  float*          eff     = (float*)(ws);                 // 33,554,432
  float*          effnorm = (float*)(ws + 33554432);      // 65,536
  _Float16*       WpT     = (_Float16*)(ws + 33619968);   // 1,572,864
  int*            fcnt    = (int*)(ws + 35192832);        // 32,768
  unsigned short* flist   = (unsigned short*)(ws + 35225600); // 1,048,576
  float*          ploss   = (float*)(ws + 36274176);      // 32,768
  // CpT region [36,306,944 .. 86,638,592): dead after effgemm; overlays:
  _Float16*       CpT     = (_Float16*)(ws + 36306944);   // 50,331,648
  float*          gv      = (float*)(ws + 36306944);      // 16,777,216
  _Float16*       ApT     = (_Float16*)(ws + 53084160);   // 8,388,608
  unsigned*       gmask   = (unsigned*)(ws + 61472768);   // 16,777,216 (in hole)
  _Float16*       BpT     = (_Float16*)(ws + 86638592);   // 16,777,216 (to 103,415,808)

  float* out_zq   = out;
  float* out_loss = out + (size_t)N_ROWS * DIM;
  float* out_idx  = out + (size_t)N_ROWS * DIM + 1;

  // 1) 3-limb pre-tiled splits for eff GEMM
  split_tiled_kernel<<<64 * 48, 256, 0, stream>>>(codebook, CpT, 2);
  split_tiled_kernel<<<2 * 48, 256, 0, stream>>>(W, WpT, 1);
  // 2) eff = codebook @ W.T (3-limb f16 MFMA, 128^2 tiles) + fused BpT f16
  effgemm128_kernel<<<512, 256, 0, stream>>>(CpT, WpT, eff, BpT);
  // 3) ||eff_k||^2
  effnorm_kernel<<<K_CB / 4, 256, 0, stream>>>(eff, effnorm);
  // 4) 1-limb pre-tiled split of z (overlays dead CpT region)
  split1_kernel<<<32 * 16, 256, 0, stream>>>(z_e, ApT);
  // 5) approx distance pass (32x32x16) + group minima + per-col masks
  dist1_kernel<<<2048, 512, 0, stream>>>(ApT, BpT, effnorm, gv, gmask);
  // 6) flag candidate groups
  flag_kernel<<<N_ROWS / 4, 256, 0, stream>>>(gv, fcnt, flist);
  // 7) exact refine on masked cols + gather z_q + loss partials
  refine_kernel<<<N_ROWS, 256, 0, stream>>>(z_e, eff, effnorm, fcnt, flist,
                                            gmask, out_zq, out_idx, ploss);
  // 8) final loss
  loss_final_kernel<<<1, 256, 0, stream>>>(ploss, out_loss);
}

// Round 5
// 466.800 us; speedup vs baseline: 1.1382x; 1.1382x over previous
//
#include <hip/hip_runtime.h>
#include <stdint.h>

// ---------------------------------------------------------------------------
// SimVQ: z_e (8192x512 f32), codebook (16384x512 f32), W (512x512 f32)
// eff = codebook @ W.T; idx[i] = argmin_k (||eff_k||^2 - 2 z_i.eff_k)
// z_q = eff[idx]; total_loss = 1.25 * mean((z_e - z_q)^2)
// out (f32): [z_q (4194304)] [loss (1)] [indices-as-float (8192)]
//
// dist1 v5: 32x32x16 f16 MFMA, SPILL-FREE re-dimension of v4:
// block tile 256x128, 8 waves (4x2), 64x64 per wave -> acc[2][2] f32x16
// (64 VGPR) + frags 64 VGPR; __launch_bounds__(512,2) grants 256-VGPR budget.
// Grid 4096, XCD supertile (16 B-half-panels = 2MB L2/XCD). r0 staging
// discipline re-counted: VMCNT(4) steady, drain at t=6. Epilogue: 32x32 C
// layout group minima + candidate-col ballots (v4-verified mapping).
// Refine: exact fp32 on masked cols only (2 KB/col).
// ---------------------------------------------------------------------------

#define N_ROWS 8192
#define DIM    512
#define K_CB   16384
#define TILE_F16 16384         // 256x64 f16 (32 KB)
#define HALF_F16 8192
#define KT_EFF 24              // eff GEMM: K'=1536
#define KT_D   8               // dist pass: K=512
#define PAN_D   ((size_t)KT_D * TILE_F16)
#define RMARGIN 4.0f

typedef _Float16 f16x8 __attribute__((ext_vector_type(8)));
typedef float f32x4 __attribute__((ext_vector_type(4)));
typedef float f32x16 __attribute__((ext_vector_type(16)));

#define FENCE() asm volatile("" ::: "memory")
#define BARRIER() do { FENCE(); __builtin_amdgcn_s_barrier(); FENCE(); } while (0)
#define VMCNT(n) asm volatile("s_waitcnt vmcnt(" #n ")" ::: "memory")

__device__ __forceinline__ void gload_lds16(const void* g, void* l) {
  __builtin_amdgcn_global_load_lds(
      (const __attribute__((address_space(1))) uint32_t*)g,
      (__attribute__((address_space(3))) uint32_t*)l, 16, 0, 0);
}

// ----------------------- shared staging building block ---------------------

__device__ __forceinline__ void stage_half(const _Float16* src, _Float16* ldsb,
                                           int w, int lane) {
  const _Float16* s = src + w * 512 + lane * 8;
  _Float16* l = ldsb + w * 512;
  gload_lds16(s, l);
  gload_lds16(s + 4096, l + 4096);
}

// -------------------- limb splits into pre-tiled layout --------------------
// 3-limb: [panel][kt(24)][half][kblk(8)][row(128)][8]; limb group per kt/8.
__global__ __launch_bounds__(256) void split_tiled_kernel(
    const float* __restrict__ S, _Float16* __restrict__ T, int resid_limb) {
  const int b = blockIdx.x;
  const int mp = b / 48;
  const int r1 = b % 48;
  const int kt = r1 >> 1, half = r1 & 1;
  const int limb = kt >> 3;
  const int ksrc = (kt & 7) * 64;
  const bool resid = (limb == resid_limb);
  const int t = threadIdx.x;
  _Float16* dst = T + ((size_t)(mp * KT_EFF + kt) * 2 + half) * HALF_F16;
#pragma unroll
  for (int cc = 0; cc < 4; ++cc) {
    const int ci = cc * 256 + t;
    const int kblk = ci >> 7, row = ci & 127;
    const int m = mp * 256 + half * 128 + row;
    const float* src = &S[(size_t)m * DIM + ksrc + kblk * 8];
    float4 x0 = *reinterpret_cast<const float4*>(src);
    float4 x1 = *reinterpret_cast<const float4*>(src + 4);
    const float xs[8] = {x0.x, x0.y, x0.z, x0.w, x1.x, x1.y, x1.z, x1.w};
    f16x8 o;
    if (!resid) {
#pragma unroll
      for (int j = 0; j < 8; ++j) o[j] = (_Float16)xs[j];
    } else {
#pragma unroll
      for (int j = 0; j < 8; ++j) {
        _Float16 h = (_Float16)xs[j];
        o[j] = (_Float16)(xs[j] - (float)h);
      }
    }
    *reinterpret_cast<f16x8*>(&dst[(size_t)ci * 8]) = o;
  }
}

// 1-limb: [panel][kt(8)][half][kblk(8)][row(128)][8]  (for z_e -> ApT)
__global__ __launch_bounds__(256) void split1_kernel(
    const float* __restrict__ S, _Float16* __restrict__ T) {
  const int b = blockIdx.x;
  const int p = b >> 4;
  const int r1 = b & 15;
  const int kt = r1 >> 1, half = r1 & 1;
  const int ksrc = kt * 64;
  const int t = threadIdx.x;
  _Float16* dst = T + ((size_t)(p * KT_D + kt) * 2 + half) * HALF_F16;
#pragma unroll
  for (int cc = 0; cc < 4; ++cc) {
    const int ci = cc * 256 + t;
    const int kblk = ci >> 7, row = ci & 127;
    const int m = p * 256 + half * 128 + row;
    const float* src = &S[(size_t)m * DIM + ksrc + kblk * 8];
    float4 x0 = *reinterpret_cast<const float4*>(src);
    float4 x1 = *reinterpret_cast<const float4*>(src + 4);
    const float xs[8] = {x0.x, x0.y, x0.z, x0.w, x1.x, x1.y, x1.z, x1.w};
    f16x8 o;
#pragma unroll
    for (int j = 0; j < 8; ++j) o[j] = (_Float16)xs[j];
    *reinterpret_cast<f16x8*>(&dst[(size_t)ci * 8]) = o;
  }
}

// ----------------- eff GEMM: 128^2 tiles, fused f16 emission ---------------
// Block: 256 thr, 4 waves (2x2 of 64x64), BK=64, double-buffered 64 KB LDS.
// Epilogue writes fp32 eff AND pre-tiled 1-limb BpT.
__global__ __launch_bounds__(256) void effgemm128_kernel(
    const _Float16* __restrict__ CpT, const _Float16* __restrict__ WpT,
    float* __restrict__ eff, _Float16* __restrict__ BpT) {
  __shared__ __align__(16) _Float16 lbuf[2][2][HALF_F16];  // 64 KB
  const int tid = threadIdx.x;
  const int w = tid >> 6, lane = tid & 63;
  const int lh = lane & 15, lq = lane >> 4;
  const int wr = w >> 1, wc = w & 1;
  const int bid = blockIdx.x;
  const int nb = bid & 3, mh = bid >> 2;       // mh: 128-row half (0..127)
  const int pA = mh >> 1, hA = mh & 1;
  const int pB = nb >> 1, hB = nb & 1;
  f32x4 acc[4][4] = {};

  // stage one kt (A-half + B-half) into buf
  auto stage = [&](int kt, int buf) {
    const _Float16* a = CpT + (((size_t)pA * KT_EFF + kt) * 2 + hA) * HALF_F16;
    const _Float16* b = WpT + (((size_t)pB * KT_EFF + kt) * 2 + hB) * HALF_F16;
#pragma unroll
    for (int i = 0; i < 4; ++i) {
      const int off = i * 2048 + w * 512;
      gload_lds16(a + off + lane * 8, &lbuf[buf][0][off]);
      gload_lds16(b + off + lane * 8, &lbuf[buf][1][off]);
    }
  };

  stage(0, 0);
  for (int kt = 0; kt < KT_EFF; ++kt) {
    __syncthreads();
    if (kt + 1 < KT_EFF) stage(kt + 1, (kt + 1) & 1);
    const _Float16* At = &lbuf[kt & 1][0][0];
    const _Float16* Bt = &lbuf[kt & 1][1][0];
    f16x8 af[4][2], bf[4][2];
#pragma unroll
    for (int mf = 0; mf < 4; ++mf) {
      const int r = wr * 64 + mf * 16 + lh;
#pragma unroll
      for (int kk = 0; kk < 2; ++kk)
        af[mf][kk] = *reinterpret_cast<const f16x8*>(
            &At[((kk * 4 + lq) * 128 + r) * 8]);
    }
#pragma unroll
    for (int nf = 0; nf < 4; ++nf) {
      const int r = wc * 64 + nf * 16 + lh;
#pragma unroll
      for (int kk = 0; kk < 2; ++kk)
        bf[nf][kk] = *reinterpret_cast<const f16x8*>(
            &Bt[((kk * 4 + lq) * 128 + r) * 8]);
    }
    __builtin_amdgcn_s_setprio(1);
#pragma unroll
    for (int mf = 0; mf < 4; ++mf)
#pragma unroll
      for (int nf = 0; nf < 4; ++nf)
#pragma unroll
        for (int kk = 0; kk < 2; ++kk)
          acc[mf][nf] = __builtin_amdgcn_mfma_f32_16x16x32_f16(
              af[mf][kk], bf[nf][kk], acc[mf][nf], 0, 0, 0);
    __builtin_amdgcn_s_setprio(0);
  }

#pragma unroll
  for (int mf = 0; mf < 4; ++mf)
#pragma unroll
    for (int nf = 0; nf < 4; ++nf)
#pragma unroll
      for (int j = 0; j < 4; ++j) {
        const int rl = wr * 64 + mf * 16 + lq * 4 + j;
        const int cl = wc * 64 + nf * 16 + lh;
        const int row = mh * 128 + rl;
        const int col = nb * 128 + cl;
        const float v = acc[mf][nf][j];
        eff[(size_t)row * DIM + col] = v;
        const int ktd = col >> 6, kblk = (col >> 3) & 7, ce = col & 7;
        BpT[((((size_t)(row >> 8) * KT_D + ktd) * 2 + ((row >> 7) & 1)) * 8 + kblk)
                * 1024 + (row & 127) * 8 + ce] = (_Float16)v;
      }
}

__global__ __launch_bounds__(256) void effnorm_kernel(
    const float* __restrict__ E, float* __restrict__ En) {
  const int w = threadIdx.x >> 6;
  const int lane = threadIdx.x & 63;
  const int row = blockIdx.x * 4 + w;
  const float* er = &E[(size_t)row * DIM];
  float s = 0.f;
#pragma unroll
  for (int k = 0; k < DIM / 64; ++k) {
    float v = er[lane + k * 64];
    s = fmaf(v, v, s);
  }
#pragma unroll
  for (int o = 32; o; o >>= 1) s += __shfl_down(s, o, 64);
  if (lane == 0) En[row] = s;
}

// ------------- dist pass 1 v5: 32x32x16, 256x128 tile, no spill ------------
// Grid 4096: xcd=bid&7, c=bid>>3; nh = xcd*16 + (c&15) (128-col half-panel),
// mp = c>>4. Block: 512 thr, 8 waves 4x2; wave output 64x64.
// LDS 96 KB: lds[2][A 32KB | B 16KB], double-buffered.
// Per K-step: early stage A(t+1)h2; 16 ds_read_b128/wave; mid-barrier; 16
// MFMA k16-outer (4 indep acc/window); stage B(t+2)+A(t+2)h1 post-MFMA;
// VMCNT(4) (FIFO: drains A(t+1)h2 + older, leaves the 4 t+2 loads); drain-0
// at t=6. A frag: row=wr*64+mi*32+l31, kblk=k16*2+kh. C frag: col=l31,
// row=(reg&3)+8*(reg>>2)+4*kh  (v4-verified mapping).
__global__ __launch_bounds__(512, 2) void dist1_kernel(
    const _Float16* __restrict__ ApT, const _Float16* __restrict__ BpT,
    const float* __restrict__ En, float* __restrict__ gv,
    unsigned* __restrict__ gmask) {
  __shared__ __align__(16) _Float16 lds[2][TILE_F16 + HALF_F16];  // 96 KB
  const int tid = threadIdx.x;
  const int w = tid >> 6, lane = tid & 63;
  const int l31 = lane & 31, kh = lane >> 5;
  const int wr = w >> 1, wc = w & 1;
  const int bid = blockIdx.x;
  const int xcd = bid & 7, c = bid >> 3;
  const int nh = xcd * 16 + (c & 15);          // 128-col half-panel (0..127)
  const int mp = c >> 4;                       // 256-row panel (0..31)
  const int np = nh >> 1, hB = nh & 1;
  const _Float16* Ab = ApT + (size_t)mp * PAN_D;

  // B source for kt: half hB of panel np
  auto Bk = [&](int kt) -> const _Float16* {
    return BpT + (((size_t)np * KT_D + kt) * 2 + hB) * HALF_F16;
  };

  float en[2];
  en[0] = En[nh * 128 + wc * 64 + l31];
  en[1] = En[nh * 128 + wc * 64 + 32 + l31];

  f32x16 acc[2][2] = {};
  f16x8 a32[2][4], b32[2][4];

  // prologue: A0h1 A0h2 B0 | B1 A1h1   (10 loads; first 6 = tile 0)
  stage_half(Ab, &lds[0][0], w, lane);
  stage_half(Ab + HALF_F16, &lds[0][HALF_F16], w, lane);
  stage_half(Bk(0), &lds[0][TILE_F16], w, lane);
  stage_half(Bk(1), &lds[1][TILE_F16], w, lane);
  stage_half(Ab + TILE_F16, &lds[1][0], w, lane);
  VMCNT(4);                      // tile 0 resident; 4 in flight (tile 1 part)
  BARRIER();

  for (int t = 0; t < KT_D; ++t) {
    const int s = t & 1;
    const _Float16* At = &lds[s][0];
    const _Float16* Bt = &lds[s][TILE_F16];
    // earliest-issue: finish tile t+1's A (that region was consumed at t-1)
    if (t + 1 < KT_D)
      stage_half(Ab + (size_t)(t + 1) * TILE_F16 + HALF_F16,
                 &lds[s ^ 1][HALF_F16], w, lane);
    // fragment reads: A 8, B 8 ds_read_b128 (quarter-waves contiguous)
#pragma unroll
    for (int mi = 0; mi < 2; ++mi) {
      const int row = wr * 64 + mi * 32 + l31;
      const int half = row >> 7, r = row & 127;
#pragma unroll
      for (int k16 = 0; k16 < 4; ++k16)
        a32[mi][k16] = *reinterpret_cast<const f16x8*>(
            &At[(((half * 8 + k16 * 2 + kh) * 128) + r) * 8]);
    }
#pragma unroll
    for (int ni = 0; ni < 2; ++ni) {
      const int rb = wc * 64 + ni * 32 + l31;
#pragma unroll
      for (int k16 = 0; k16 < 4; ++k16)
        b32[ni][k16] = *reinterpret_cast<const f16x8*>(
            &Bt[(((k16 * 2 + kh) * 128) + rb) * 8]);
    }
    BARRIER();  // all waves issued reads of bufs s before overwrites below
    __builtin_amdgcn_s_setprio(1);
#pragma unroll
    for (int k16 = 0; k16 < 4; ++k16)
#pragma unroll
      for (int mi = 0; mi < 2; ++mi)
#pragma unroll
        for (int ni = 0; ni < 2; ++ni)
          acc[mi][ni] = __builtin_amdgcn_mfma_f32_32x32x16_f16(
              a32[mi][k16], b32[ni][k16], acc[mi][ni], 0, 0, 0);
    __builtin_amdgcn_s_setprio(0);
    // post-MFMA staging of tile t+2 into the buffer read THIS step (safe:
    // staging writes land >= global latency after the mid-barrier read-issue)
    if (t + 2 < KT_D) {
      stage_half(Bk(t + 2), &lds[s][TILE_F16], w, lane);
      stage_half(Ab + (size_t)(t + 2) * TILE_F16, &lds[s][0], w, lane);
    }
    if (t == KT_D - 2) { VMCNT(0); BARRIER(); }
    else if (t + 1 < KT_D) { VMCNT(4); BARRIER(); }
  }

  // epilogue: fold En, per-32col-group minima + candidate-col ballots.
  // Each 32-lane half spans one 32-col group; halves hold rows r and r+4.
#pragma unroll
  for (int mi = 0; mi < 2; ++mi)
#pragma unroll
    for (int ni = 0; ni < 2; ++ni) {
#pragma unroll
      for (int reg = 0; reg < 16; ++reg) {
        const float sc = fmaf(-2.f, acc[mi][ni][reg], en[ni]);
        float g = sc;
#pragma unroll
        for (int m = 1; m < 32; m <<= 1) g = fminf(g, __shfl_xor(g, m, 64));
        const unsigned long long b = __ballot(sc <= g + RMARGIN);
        if (l31 == 0) {
          const int row = mp * 256 + wr * 64 + mi * 32 +
                          (reg & 3) + 8 * (reg >> 2) + 4 * kh;
          const int gidx = nh * 4 + wc * 2 + ni;
          gv[(size_t)row * 512 + gidx] = g;
          gmask[(size_t)row * 512 + gidx] = (unsigned)(b >> (kh * 32));
        }
      }
    }
}

// ------------------------------- flag pass ---------------------------------
__global__ __launch_bounds__(256) void flag_kernel(
    const float* __restrict__ gv, int* __restrict__ fcnt,
    unsigned short* __restrict__ flist) {
  const int t = threadIdx.x;
  const int w = t >> 6, lane = t & 63;
  const int row = blockIdx.x * 4 + w;
  float v[8];
#pragma unroll
  for (int i = 0; i < 8; ++i) v[i] = gv[(size_t)row * 512 + i * 64 + lane];
  float A = v[0];
#pragma unroll
  for (int i = 1; i < 8; ++i) A = fminf(A, v[i]);
#pragma unroll
  for (int m = 1; m < 64; m <<= 1) A = fminf(A, __shfl_xor(A, m, 64));
  __shared__ int cnt[4];
  __shared__ unsigned short lst[4][64];
  if (lane == 0) cnt[w] = 0;
  __syncthreads();
  const float thr = A + RMARGIN;
#pragma unroll
  for (int i = 0; i < 8; ++i) {
    if (v[i] <= thr) {
      int p = atomicAdd(&cnt[w], 1);
      if (p < 64) lst[w][p] = (unsigned short)(i * 64 + lane);
    }
  }
  __syncthreads();
  const int cn = cnt[w];
  if (lane == 0) fcnt[row] = (cn > 64) ? -1 : cn;
  if (lane < cn && lane < 64) flist[(size_t)row * 64 + lane] = lst[w][lane];
}

// ------- refine v2: masked cols only, wave-per-group, no in-loop sync ------
__global__ __launch_bounds__(256) void refine_kernel(
    const float* __restrict__ Z, const float* __restrict__ E,
    const float* __restrict__ En, const int* __restrict__ fcnt,
    const unsigned short* __restrict__ flist, const unsigned* __restrict__ gmask,
    float* __restrict__ zq, float* __restrict__ out_idx,
    float* __restrict__ ploss) {
  const int row = blockIdx.x;
  const int t = threadIdx.x;
  const int w = t >> 6, lane = t & 63;
  const int hl = lane & 31;
  const int hi = lane >> 5;
  __shared__ float zrow[512];
  __shared__ unsigned short glist[512];
  __shared__ float bvs[4];
  __shared__ int bis[4];
  __shared__ int sidx;
  __shared__ float wsum[4];
  if (t < 128)
    ((float4*)zrow)[t] = ((const float4*)(Z + (size_t)row * 512))[t];
  const int cr = fcnt[row];
  int ng;
  if (cr < 0) {
    glist[t] = (unsigned short)t;
    glist[t + 256] = (unsigned short)(t + 256);
    ng = 512;
  } else {
    ng = cr;
    if (t < cr) glist[t] = flist[(size_t)row * 64 + t];
  }
  // per-lane z chunk: dims hl*16 .. hl*16+15 (same for both halves)
  float4 zr0, zr1, zr2, zr3;
  {
    const float4* zp = (const float4*)(Z + (size_t)row * 512 + hl * 16);
    zr0 = zp[0]; zr1 = zp[1]; zr2 = zp[2]; zr3 = zp[3];
  }
  __syncthreads();

  float bv = 3.0e38f;
  int bi = 2147483647;
  for (int q = w; q < ng; q += 4) {
    const int g = glist[q];
    unsigned m = gmask[(size_t)row * 512 + g];
    while (m) {
      const int c0 = __builtin_ctz(m);
      m &= m - 1;
      int c1 = -1;
      if (m) { c1 = __builtin_ctz(m); m &= m - 1; }
      const int cl = hi ? c1 : c0;
      const bool act = (cl >= 0);
      const int col = g * 32 + (act ? cl : c0);
      const float4* er = (const float4*)(E + (size_t)col * 512 + hl * 16);
      const float4 e0 = er[0], e1 = er[1], e2 = er[2], e3 = er[3];
      float p = 0.f;
      p = fmaf(zr0.x, e0.x, p); p = fmaf(zr0.y, e0.y, p);
      p = fmaf(zr0.z, e0.z, p); p = fmaf(zr0.w, e0.w, p);
      p = fmaf(zr1.x, e1.x, p); p = fmaf(zr1.y, e1.y, p);
      p = fmaf(zr1.z, e1.z, p); p = fmaf(zr1.w, e1.w, p);
      p = fmaf(zr2.x, e2.x, p); p = fmaf(zr2.y, e2.y, p);
      p = fmaf(zr2.z, e2.z, p); p = fmaf(zr2.w, e2.w, p);
      p = fmaf(zr3.x, e3.x, p); p = fmaf(zr3.y, e3.y, p);
      p = fmaf(zr3.z, e3.z, p); p = fmaf(zr3.w, e3.w, p);
#pragma unroll
      for (int s2 = 1; s2 < 32; s2 <<= 1) p += __shfl_xor(p, s2, 64);
      const float v = fmaf(-2.f, p, En[col]);
      if (act && (v < bv || (v == bv && col < bi))) { bv = v; bi = col; }
    }
  }
#pragma unroll
  for (int s2 = 1; s2 < 64; s2 <<= 1) {
    const float v2 = __shfl_xor(bv, s2, 64);
    const int i2 = __shfl_xor(bi, s2, 64);
    if (v2 < bv || (v2 == bv && i2 < bi)) { bv = v2; bi = i2; }
  }
  if (lane == 0) { bvs[w] = bv; bis[w] = bi; }
  __syncthreads();
  if (t == 0) {
    float fb = bvs[0];
    int fi = bis[0];
#pragma unroll
    for (int i = 1; i < 4; ++i)
      if (bvs[i] < fb || (bvs[i] == fb && bis[i] < fi)) { fb = bvs[i]; fi = bis[i]; }
    sidx = fi;
  }
  __syncthreads();
  const int idx = sidx;

  float s = 0.f;
  const float* erow = E + (size_t)idx * 512;
#pragma unroll
  for (int d0 = 0; d0 < 512; d0 += 256) {
    const int d = d0 + t;
    const float e = erow[d];
    const float z = zrow[d];
    zq[(size_t)row * 512 + d] = e;
    const float df = z - e;
    s = fmaf(df, df, s);
  }
#pragma unroll
  for (int o = 32; o; o >>= 1) s += __shfl_down(s, o, 64);
  if ((t & 63) == 0) wsum[t >> 6] = s;
  __syncthreads();
  if (t == 0) {
    ploss[row] = wsum[0] + wsum[1] + wsum[2] + wsum[3];
    out_idx[row] = (float)idx;
  }
}

__global__ __launch_bounds__(256) void loss_final_kernel(
    const float* __restrict__ ploss, float* __restrict__ out_loss) {
  const int t = threadIdx.x;
  double s = 0.0;
  for (int i = t; i < N_ROWS; i += 256) s += (double)ploss[i];
#pragma unroll
  for (int o = 32; o; o >>= 1) s += __shfl_down(s, o, 64);
  __shared__ double ds[4];
  if ((t & 63) == 0) ds[t >> 6] = s;
  __syncthreads();
  if (t == 0) {
    double tot = ds[0] + ds[1] + ds[2] + ds[3];
    out_loss[0] = (float)(1.25 * tot / ((double)N_ROWS * (double)DIM));
  }
}

// --------------------------------- launch ----------------------------------

extern "C" void kernel_launch(void* const* d_in, const int* in_sizes, int n_in,
                              void* d_out, int out_size, void* d_ws, size_t ws_size,
                              hipStream_t stream) {
  const float* z_e      = (const float*)d_in[0];
  const float* codebook = (const float*)d_in[1];
  const float* W        = (const float*)d_in[2];
  float* out = (float*)d_out;
  char* ws = (char*)d_ws;

  float*          eff     = (float*)(ws);                 // 33,554,432
  float*          effnorm = (float*)(ws + 33554432);      // 65,536
  _Float16*       WpT     = (_Float16*)(ws + 33619968);   // 1,572,864
  int*            fcnt    = (int*)(ws + 35192832);        // 32,768
  unsigned short* flist   = (unsigned short*)(ws + 35225600); // 1,048,576
  float*          ploss   = (float*)(ws + 36274176);      // 32,768
  // CpT region [36,306,944 .. 86,638,592): dead after effgemm; overlays:
  _Float16*       CpT     = (_Float16*)(ws + 36306944);   // 50,331,648
  float*          gv      = (float*)(ws + 36306944);      // 16,777,216
  _Float16*       ApT     = (_Float16*)(ws + 53084160);   // 8,388,608
  unsigned*       gmask   = (unsigned*)(ws + 61472768);   // 16,777,216 (in hole)
  _Float16*       BpT     = (_Float16*)(ws + 86638592);   // 16,777,216 (to 103,415,808)

  float* out_zq   = out;
  float* out_loss = out + (size_t)N_ROWS * DIM;
  float* out_idx  = out + (size_t)N_ROWS * DIM + 1;

  // 1) 3-limb pre-tiled splits for eff GEMM
  split_tiled_kernel<<<64 * 48, 256, 0, stream>>>(codebook, CpT, 2);
  split_tiled_kernel<<<2 * 48, 256, 0, stream>>>(W, WpT, 1);
  // 2) eff = codebook @ W.T (3-limb f16 MFMA, 128^2 tiles) + fused BpT f16
  effgemm128_kernel<<<512, 256, 0, stream>>>(CpT, WpT, eff, BpT);
  // 3) ||eff_k||^2
  effnorm_kernel<<<K_CB / 4, 256, 0, stream>>>(eff, effnorm);
  // 4) 1-limb pre-tiled split of z (overlays dead CpT region)
  split1_kernel<<<32 * 16, 256, 0, stream>>>(z_e, ApT);
  // 5) approx distance pass (32x32x16, 256x128 tiles) + minima + masks
  dist1_kernel<<<4096, 512, 0, stream>>>(ApT, BpT, effnorm, gv, gmask);
  // 6) flag candidate groups
  flag_kernel<<<N_ROWS / 4, 256, 0, stream>>>(gv, fcnt, flist);
  // 7) exact refine on masked cols + gather z_q + loss partials
  refine_kernel<<<N_ROWS, 256, 0, stream>>>(z_e, eff, effnorm, fcnt, flist,
                                            gmask, out_zq, out_idx, ploss);
  // 8) final loss
  loss_final_kernel<<<1, 256, 0, stream>>>(ploss, out_loss);
}

// Round 6
// 281.150 us; speedup vs baseline: 1.8897x; 1.6603x over previous
//
#include <hip/hip_runtime.h>
#include <stdint.h>

// ---------------------------------------------------------------------------
// SimVQ: z_e (8192x512 f32), codebook (16384x512 f32), W (512x512 f32)
// eff = codebook @ W.T; idx[i] = argmin_k (||eff_k||^2 - 2 z_i.eff_k)
// z_q = eff[idx]; total_loss = 1.25 * mean((z_e - z_q)^2)
// out (f32): [z_q (4194304)] [loss (1)] [indices-as-float (8192)]
//
// eff GEMM: 3-limb f16 MFMA, 128^2 tiles; epilogue writes fp32 eff AND the
// pre-tiled 1-limb f16 BpT for the dist pass.
// dist1: r0/r3 8-phase 256^2 structure (best measured), kk-outer MFMA order
// (independent-acc window of 8; per-acc order unchanged -> bit-identical),
// epilogue emits group minima + candidate-col ballot masks.
// refine v3: flag fused in; wave-per-row (2048 blocks x 4 waves, no syncs);
// exact fp32 dots on masked cols only (2 KB/col), same dot order as r3.
// ---------------------------------------------------------------------------

#define N_ROWS 8192
#define DIM    512
#define K_CB   16384
#define TILE_F16 16384         // 256x64 f16 (32 KB)
#define HALF_F16 8192
#define KT_EFF 24              // eff GEMM: K'=1536
#define KT_D   8               // dist pass: K=512
#define PAN_D   ((size_t)KT_D * TILE_F16)
#define RMARGIN 4.0f

typedef _Float16 f16x8 __attribute__((ext_vector_type(8)));
typedef float f32x4 __attribute__((ext_vector_type(4)));

#define FENCE() asm volatile("" ::: "memory")
#define BARRIER() do { FENCE(); __builtin_amdgcn_s_barrier(); FENCE(); } while (0)
#define VMCNT(n) asm volatile("s_waitcnt vmcnt(" #n ")" ::: "memory")

__device__ __forceinline__ void gload_lds16(const void* g, void* l) {
  __builtin_amdgcn_global_load_lds(
      (const __attribute__((address_space(1))) uint32_t*)g,
      (__attribute__((address_space(3))) uint32_t*)l, 16, 0, 0);
}

// ----------------------- 256^2 8-phase GEMM pieces -------------------------

__device__ __forceinline__ void stage_half(const _Float16* src, _Float16* ldsb,
                                           int w, int lane) {
  const _Float16* s = src + w * 512 + lane * 8;
  _Float16* l = ldsb + w * 512;
  gload_lds16(s, l);
  gload_lds16(s + 4096, l + 4096);
}

template <int MQ>
__device__ __forceinline__ void read_a(const _Float16* At, int wr, int lh, int lq,
                                       f16x8 af[4][2]) {
#pragma unroll
  for (int m2 = 0; m2 < 4; ++m2) {
    const int row = wr * 128 + (MQ * 4 + m2) * 16 + lh;
    const int half = row >> 7, r = row & 127;
#pragma unroll
    for (int kk = 0; kk < 2; ++kk) {
      const int kblk = kk * 4 + lq;
      af[m2][kk] = *reinterpret_cast<const f16x8*>(
          &At[(((size_t)(half * 8 + kblk)) * 128 + r) * 8]);
    }
  }
}

template <int NQ>
__device__ __forceinline__ void read_b(const _Float16* Bt, int wc, int lh, int lq,
                                       f16x8 bf[4][2]) {
#pragma unroll
  for (int n2 = 0; n2 < 2; ++n2) {
    const int row = wc * 64 + (NQ * 2 + n2) * 16 + lh;
    const int half = row >> 7, r = row & 127;
#pragma unroll
    for (int kk = 0; kk < 2; ++kk) {
      const int kblk = kk * 4 + lq;
      bf[NQ * 2 + n2][kk] = *reinterpret_cast<const f16x8*>(
          &Bt[(((size_t)(half * 8 + kblk)) * 128 + r) * 8]);
    }
  }
}

// kk OUTERMOST: 8 independent accumulators between same-acc reuse (was kk
// innermost = dependent back-to-back pairs). Per-acc order still kk=0,1 ->
// bitwise-identical results.
template <int MQ, int NQ>
__device__ __forceinline__ void mfma_phase(const f16x8 af[4][2],
                                           const f16x8 bf[4][2],
                                           f32x4 acc[8][4]) {
  __builtin_amdgcn_s_setprio(1);
#pragma unroll
  for (int kk = 0; kk < 2; ++kk)
#pragma unroll
    for (int m2 = 0; m2 < 4; ++m2)
#pragma unroll
      for (int n2 = 0; n2 < 2; ++n2)
        acc[MQ * 4 + m2][NQ * 2 + n2] = __builtin_amdgcn_mfma_f32_16x16x32_f16(
            af[m2][kk], bf[NQ * 2 + n2][kk], acc[MQ * 4 + m2][NQ * 2 + n2], 0, 0, 0);
  __builtin_amdgcn_s_setprio(0);
}

__device__ __forceinline__ void pipeline8(
    const _Float16* Abase, const _Float16* Bbase,
    _Float16 (&lds)[4][TILE_F16], f32x4 (&acc)[8][4],
    int w, int lane, int wr, int wc, int lh, int lq, int NT) {
  f16x8 af[4][2], bf[4][2];
  stage_half(Abase, &lds[0][0], w, lane);
  stage_half(Abase + HALF_F16, &lds[0][HALF_F16], w, lane);
  stage_half(Bbase, &lds[1][0], w, lane);
  stage_half(Bbase + HALF_F16, &lds[1][HALF_F16], w, lane);
  stage_half(Bbase + TILE_F16, &lds[3][0], w, lane);
  stage_half(Bbase + TILE_F16 + HALF_F16, &lds[3][HALF_F16], w, lane);
  stage_half(Abase + TILE_F16, &lds[2][0], w, lane);
  VMCNT(6);
  BARRIER();
  for (int t = 0; t < NT; ++t) {
    const int s = t & 1;
    const _Float16* At = &lds[s * 2 + 0][0];
    const _Float16* Bt = &lds[s * 2 + 1][0];
    read_a<0>(At, wr, lh, lq, af);
    read_b<0>(Bt, wc, lh, lq, bf);
    if (t + 1 < NT)
      stage_half(Abase + (size_t)(t + 1) * TILE_F16 + HALF_F16,
                 &lds[(s ^ 1) * 2][HALF_F16], w, lane);
    BARRIER();
    mfma_phase<0, 0>(af, bf, acc);
    BARRIER();
    read_b<1>(Bt, wc, lh, lq, bf);
    BARRIER();
    mfma_phase<0, 1>(af, bf, acc);
    BARRIER();
    read_a<1>(At, wr, lh, lq, af);
    if (t + 2 < NT)
      stage_half(Bbase + (size_t)(t + 2) * TILE_F16, &lds[s * 2 + 1][0], w, lane);
    BARRIER();
    mfma_phase<1, 1>(af, bf, acc);
    BARRIER();
    if (t + 2 < NT) {
      stage_half(Bbase + (size_t)(t + 2) * TILE_F16 + HALF_F16,
                 &lds[s * 2 + 1][HALF_F16], w, lane);
      stage_half(Abase + (size_t)(t + 2) * TILE_F16, &lds[s * 2][0], w, lane);
    }
    BARRIER();
    mfma_phase<1, 0>(af, bf, acc);
    if (t == NT - 2) { VMCNT(0); } else { VMCNT(6); }
    BARRIER();
  }
}

// -------------------- limb splits into pre-tiled layout --------------------
// 3-limb: [panel][kt(24)][half][kblk(8)][row(128)][8]; limb group per kt/8.
__global__ __launch_bounds__(256) void split_tiled_kernel(
    const float* __restrict__ S, _Float16* __restrict__ T, int resid_limb) {
  const int b = blockIdx.x;
  const int mp = b / 48;
  const int r1 = b % 48;
  const int kt = r1 >> 1, half = r1 & 1;
  const int limb = kt >> 3;
  const int ksrc = (kt & 7) * 64;
  const bool resid = (limb == resid_limb);
  const int t = threadIdx.x;
  _Float16* dst = T + ((size_t)(mp * KT_EFF + kt) * 2 + half) * HALF_F16;
#pragma unroll
  for (int cc = 0; cc < 4; ++cc) {
    const int ci = cc * 256 + t;
    const int kblk = ci >> 7, row = ci & 127;
    const int m = mp * 256 + half * 128 + row;
    const float* src = &S[(size_t)m * DIM + ksrc + kblk * 8];
    float4 x0 = *reinterpret_cast<const float4*>(src);
    float4 x1 = *reinterpret_cast<const float4*>(src + 4);
    const float xs[8] = {x0.x, x0.y, x0.z, x0.w, x1.x, x1.y, x1.z, x1.w};
    f16x8 o;
    if (!resid) {
#pragma unroll
      for (int j = 0; j < 8; ++j) o[j] = (_Float16)xs[j];
    } else {
#pragma unroll
      for (int j = 0; j < 8; ++j) {
        _Float16 h = (_Float16)xs[j];
        o[j] = (_Float16)(xs[j] - (float)h);
      }
    }
    *reinterpret_cast<f16x8*>(&dst[(size_t)ci * 8]) = o;
  }
}

// 1-limb: [panel][kt(8)][half][kblk(8)][row(128)][8]  (for z_e -> ApT)
__global__ __launch_bounds__(256) void split1_kernel(
    const float* __restrict__ S, _Float16* __restrict__ T) {
  const int b = blockIdx.x;
  const int p = b >> 4;
  const int r1 = b & 15;
  const int kt = r1 >> 1, half = r1 & 1;
  const int ksrc = kt * 64;
  const int t = threadIdx.x;
  _Float16* dst = T + ((size_t)(p * KT_D + kt) * 2 + half) * HALF_F16;
#pragma unroll
  for (int cc = 0; cc < 4; ++cc) {
    const int ci = cc * 256 + t;
    const int kblk = ci >> 7, row = ci & 127;
    const int m = p * 256 + half * 128 + row;
    const float* src = &S[(size_t)m * DIM + ksrc + kblk * 8];
    float4 x0 = *reinterpret_cast<const float4*>(src);
    float4 x1 = *reinterpret_cast<const float4*>(src + 4);
    const float xs[8] = {x0.x, x0.y, x0.z, x0.w, x1.x, x1.y, x1.z, x1.w};
    f16x8 o;
#pragma unroll
    for (int j = 0; j < 8; ++j) o[j] = (_Float16)xs[j];
    *reinterpret_cast<f16x8*>(&dst[(size_t)ci * 8]) = o;
  }
}

// ----------------- eff GEMM: 128^2 tiles, fused f16 emission ---------------
// Block: 256 thr, 4 waves (2x2 of 64x64), BK=64, double-buffered 64 KB LDS.
// Epilogue writes fp32 eff AND pre-tiled 1-limb BpT.
__global__ __launch_bounds__(256) void effgemm128_kernel(
    const _Float16* __restrict__ CpT, const _Float16* __restrict__ WpT,
    float* __restrict__ eff, _Float16* __restrict__ BpT) {
  __shared__ __align__(16) _Float16 lbuf[2][2][HALF_F16];  // 64 KB
  const int tid = threadIdx.x;
  const int w = tid >> 6, lane = tid & 63;
  const int lh = lane & 15, lq = lane >> 4;
  const int wr = w >> 1, wc = w & 1;
  const int bid = blockIdx.x;
  const int nb = bid & 3, mh = bid >> 2;       // mh: 128-row half (0..127)
  const int pA = mh >> 1, hA = mh & 1;
  const int pB = nb >> 1, hB = nb & 1;
  f32x4 acc[4][4] = {};

  // stage one kt (A-half + B-half) into buf
  auto stage = [&](int kt, int buf) {
    const _Float16* a = CpT + (((size_t)pA * KT_EFF + kt) * 2 + hA) * HALF_F16;
    const _Float16* b = WpT + (((size_t)pB * KT_EFF + kt) * 2 + hB) * HALF_F16;
#pragma unroll
    for (int i = 0; i < 4; ++i) {
      const int off = i * 2048 + w * 512;
      gload_lds16(a + off + lane * 8, &lbuf[buf][0][off]);
      gload_lds16(b + off + lane * 8, &lbuf[buf][1][off]);
    }
  };

  stage(0, 0);
  for (int kt = 0; kt < KT_EFF; ++kt) {
    __syncthreads();
    if (kt + 1 < KT_EFF) stage(kt + 1, (kt + 1) & 1);
    const _Float16* At = &lbuf[kt & 1][0][0];
    const _Float16* Bt = &lbuf[kt & 1][1][0];
    f16x8 af[4][2], bf[4][2];
#pragma unroll
    for (int mf = 0; mf < 4; ++mf) {
      const int r = wr * 64 + mf * 16 + lh;
#pragma unroll
      for (int kk = 0; kk < 2; ++kk)
        af[mf][kk] = *reinterpret_cast<const f16x8*>(
            &At[((kk * 4 + lq) * 128 + r) * 8]);
    }
#pragma unroll
    for (int nf = 0; nf < 4; ++nf) {
      const int r = wc * 64 + nf * 16 + lh;
#pragma unroll
      for (int kk = 0; kk < 2; ++kk)
        bf[nf][kk] = *reinterpret_cast<const f16x8*>(
            &Bt[((kk * 4 + lq) * 128 + r) * 8]);
    }
    __builtin_amdgcn_s_setprio(1);
#pragma unroll
    for (int kk = 0; kk < 2; ++kk)      // kk outer: 16 indep acc per pass
#pragma unroll
      for (int mf = 0; mf < 4; ++mf)
#pragma unroll
        for (int nf = 0; nf < 4; ++nf)
          acc[mf][nf] = __builtin_amdgcn_mfma_f32_16x16x32_f16(
              af[mf][kk], bf[nf][kk], acc[mf][nf], 0, 0, 0);
    __builtin_amdgcn_s_setprio(0);
  }

#pragma unroll
  for (int mf = 0; mf < 4; ++mf)
#pragma unroll
    for (int nf = 0; nf < 4; ++nf)
#pragma unroll
      for (int j = 0; j < 4; ++j) {
        const int rl = wr * 64 + mf * 16 + lq * 4 + j;
        const int cl = wc * 64 + nf * 16 + lh;
        const int row = mh * 128 + rl;
        const int col = nb * 128 + cl;
        const float v = acc[mf][nf][j];
        eff[(size_t)row * DIM + col] = v;
        const int ktd = col >> 6, kblk = (col >> 3) & 7, ce = col & 7;
        BpT[((((size_t)(row >> 8) * KT_D + ktd) * 2 + ((row >> 7) & 1)) * 8 + kblk)
                * 1024 + (row & 127) * 8 + ce] = (_Float16)v;
      }
}

__global__ __launch_bounds__(256) void effnorm_kernel(
    const float* __restrict__ E, float* __restrict__ En) {
  const int w = threadIdx.x >> 6;
  const int lane = threadIdx.x & 63;
  const int row = blockIdx.x * 4 + w;
  const float* er = &E[(size_t)row * DIM];
  float s = 0.f;
#pragma unroll
  for (int k = 0; k < DIM / 64; ++k) {
    float v = er[lane + k * 64];
    s = fmaf(v, v, s);
  }
#pragma unroll
  for (int o = 32; o; o >>= 1) s += __shfl_down(s, o, 64);
  if (lane == 0) En[row] = s;
}

// --------------------- dist pass 1: 1-limb + group minima ------------------
// r3 structure. Epilogue emits group minima + per-column candidate masks:
// bit k of gmask[row][G] = (score(col G*32+k) <= groupmin + RMARGIN). Since
// groupmin >= rowmin, this is a SUPERSET of cols within RMARGIN of rowmin,
// so masked-col refine preserves the exact argmin guarantee.
__global__ __launch_bounds__(512) void dist1_kernel(
    const _Float16* __restrict__ ApT, const _Float16* __restrict__ BpT,
    const float* __restrict__ En, float* __restrict__ gv,
    unsigned* __restrict__ gmask) {
  __shared__ __align__(16) _Float16 lds[4][TILE_F16];
  const int tid = threadIdx.x;
  const int w = tid >> 6, lane = tid & 63;
  const int lh = lane & 15, lq = lane >> 4;
  const int wr = w >> 2, wc = w & 3;
  // L2 supertile: per XCD, B-octet (8 np) resident; mp advances slowly.
  const int bid = blockIdx.x;
  const int xcd = bid & 7, c = bid >> 3;
  const int np = xcd * 8 + (c & 7);
  const int mp = c >> 3;
  f32x4 acc[8][4] = {};
  pipeline8(ApT + (size_t)mp * PAN_D, BpT + (size_t)np * PAN_D, lds, acc,
            w, lane, wr, wc, lh, lq, KT_D);
  float en[4];
#pragma unroll
  for (int nf = 0; nf < 4; ++nf)
    en[nf] = En[np * 256 + wc * 64 + nf * 16 + lh];
#pragma unroll
  for (int mf = 0; mf < 8; ++mf) {
#pragma unroll
    for (int j = 0; j < 4; ++j) {
      const float s0 = fmaf(-2.f, acc[mf][0][j], en[0]);
      const float s1 = fmaf(-2.f, acc[mf][1][j], en[1]);
      const float s2 = fmaf(-2.f, acc[mf][2][j], en[2]);
      const float s3 = fmaf(-2.f, acc[mf][3][j], en[3]);
      float v0 = fminf(s0, s1);
      float v1 = fminf(s2, s3);
#pragma unroll
      for (int m = 1; m < 16; m <<= 1) {
        v0 = fminf(v0, __shfl_xor(v0, m, 64));
        v1 = fminf(v1, __shfl_xor(v1, m, 64));
      }
      // per-col candidate bits (each lq quartile = one output row; the
      // ballot packs 4 rows x 16 lh cols; slice by lq*16)
      const unsigned long long b0 = __ballot(s0 <= v0 + RMARGIN);
      const unsigned long long b1 = __ballot(s1 <= v0 + RMARGIN);
      const unsigned long long b2 = __ballot(s2 <= v1 + RMARGIN);
      const unsigned long long b3 = __ballot(s3 <= v1 + RMARGIN);
      if (lh == 0) {
        const int row = mp * 256 + wr * 128 + mf * 16 + lq * 4 + j;
        const unsigned w0 = (unsigned)((b0 >> (lq * 16)) & 0xFFFFull) |
                            ((unsigned)((b1 >> (lq * 16)) & 0xFFFFull) << 16);
        const unsigned w1 = (unsigned)((b2 >> (lq * 16)) & 0xFFFFull) |
                            ((unsigned)((b3 >> (lq * 16)) & 0xFFFFull) << 16);
        float2* gp = (float2*)&gv[(size_t)row * 512 + np * 8 + wc * 2];
        *gp = make_float2(v0, v1);
        uint2* mq = (uint2*)&gmask[(size_t)row * 512 + np * 8 + wc * 2];
        *mq = make_uint2(w0, w1);
      }
    }
  }
}

// ---------- refine v3: fused flag, wave-per-row, masked cols only ----------
// Grid 2048 x 256 thr: 4 independent waves, one row each, NO block syncs.
// Per row: load 512 group minima (8/lane) -> row min; ballot-iterate flagged
// groups (gmin <= rowmin+RMARGIN, no cap); per group walk masked cols 2 at a
// time (32 lanes/col, 16 dims/lane, 5-step shfl tree -- same dot order as the
// r3-verified kernel); wave argmin; gather z_q + loss partial.
__global__ __launch_bounds__(256) void refine_kernel(
    const float* __restrict__ Z, const float* __restrict__ E,
    const float* __restrict__ En, const float* __restrict__ gv,
    const unsigned* __restrict__ gmask, float* __restrict__ zq,
    float* __restrict__ out_idx, float* __restrict__ ploss) {
  const int row = blockIdx.x * 4 + (threadIdx.x >> 6);
  const int lane = threadIdx.x & 63;
  const int hl = lane & 31;
  const int hi = lane >> 5;

  // row minimum over the 512 group minima
  float v[8];
#pragma unroll
  for (int i = 0; i < 8; ++i) v[i] = gv[(size_t)row * 512 + i * 64 + lane];
  float A = fminf(fminf(fminf(v[0], v[1]), fminf(v[2], v[3])),
                  fminf(fminf(v[4], v[5]), fminf(v[6], v[7])));
#pragma unroll
  for (int m = 1; m < 64; m <<= 1) A = fminf(A, __shfl_xor(A, m, 64));
  const float thr = A + RMARGIN;

  // per-lane z chunk: dims hl*16 .. hl*16+15 (both halves identical)
  float4 zr0, zr1, zr2, zr3;
  {
    const float4* zp = (const float4*)(Z + (size_t)row * 512 + hl * 16);
    zr0 = zp[0]; zr1 = zp[1]; zr2 = zp[2]; zr3 = zp[3];
  }

  float bv = 3.0e38f;
  int bi = 2147483647;
#pragma unroll 1
  for (int i = 0; i < 8; ++i) {
    unsigned long long bm = __ballot(v[i] <= thr);
    while (bm) {
      const int l = __builtin_ctzll(bm);
      bm &= bm - 1;
      const int g = i * 64 + l;
      unsigned m = gmask[(size_t)row * 512 + g];
      while (m) {
        const int c0 = __builtin_ctz(m);
        m &= m - 1;
        int c1 = -1;
        if (m) { c1 = __builtin_ctz(m); m &= m - 1; }
        const int cl = hi ? c1 : c0;
        const bool act = (cl >= 0);
        const int col = g * 32 + (act ? cl : c0);
        const float4* er = (const float4*)(E + (size_t)col * 512 + hl * 16);
        const float4 e0 = er[0], e1 = er[1], e2 = er[2], e3 = er[3];
        float p = 0.f;
        p = fmaf(zr0.x, e0.x, p); p = fmaf(zr0.y, e0.y, p);
        p = fmaf(zr0.z, e0.z, p); p = fmaf(zr0.w, e0.w, p);
        p = fmaf(zr1.x, e1.x, p); p = fmaf(zr1.y, e1.y, p);
        p = fmaf(zr1.z, e1.z, p); p = fmaf(zr1.w, e1.w, p);
        p = fmaf(zr2.x, e2.x, p); p = fmaf(zr2.y, e2.y, p);
        p = fmaf(zr2.z, e2.z, p); p = fmaf(zr2.w, e2.w, p);
        p = fmaf(zr3.x, e3.x, p); p = fmaf(zr3.y, e3.y, p);
        p = fmaf(zr3.z, e3.z, p); p = fmaf(zr3.w, e3.w, p);
#pragma unroll
        for (int s2 = 1; s2 < 32; s2 <<= 1) p += __shfl_xor(p, s2, 64);
        const float vv = fmaf(-2.f, p, En[col]);
        if (act && (vv < bv || (vv == bv && col < bi))) { bv = vv; bi = col; }
      }
    }
  }
#pragma unroll
  for (int s2 = 1; s2 < 64; s2 <<= 1) {
    const float v2 = __shfl_xor(bv, s2, 64);
    const int i2 = __shfl_xor(bi, s2, 64);
    if (v2 < bv || (v2 == bv && i2 < bi)) { bv = v2; bi = i2; }
  }
  const int idx = bi;  // uniform across the wave after full reduce

  // gather z_q + loss partial (8 dims/lane, vectorized)
  const float4* e4 = (const float4*)(E + (size_t)idx * 512 + lane * 8);
  const float4* z4 = (const float4*)(Z + (size_t)row * 512 + lane * 8);
  float4* q4 = (float4*)(zq + (size_t)row * 512 + lane * 8);
  const float4 ea = e4[0], eb = e4[1];
  const float4 za = z4[0], zb = z4[1];
  q4[0] = ea; q4[1] = eb;
  float s = 0.f;
  s = fmaf(za.x - ea.x, za.x - ea.x, s); s = fmaf(za.y - ea.y, za.y - ea.y, s);
  s = fmaf(za.z - ea.z, za.z - ea.z, s); s = fmaf(za.w - ea.w, za.w - ea.w, s);
  s = fmaf(zb.x - eb.x, zb.x - eb.x, s); s = fmaf(zb.y - eb.y, zb.y - eb.y, s);
  s = fmaf(zb.z - eb.z, zb.z - eb.z, s); s = fmaf(zb.w - eb.w, zb.w - eb.w, s);
#pragma unroll
  for (int o = 32; o; o >>= 1) s += __shfl_down(s, o, 64);
  if (lane == 0) {
    ploss[row] = s;
    out_idx[row] = (float)idx;
  }
}

__global__ __launch_bounds__(256) void loss_final_kernel(
    const float* __restrict__ ploss, float* __restrict__ out_loss) {
  const int t = threadIdx.x;
  double s = 0.0;
  for (int i = t; i < N_ROWS; i += 256) s += (double)ploss[i];
#pragma unroll
  for (int o = 32; o; o >>= 1) s += __shfl_down(s, o, 64);
  __shared__ double ds[4];
  if ((t & 63) == 0) ds[t >> 6] = s;
  __syncthreads();
  if (t == 0) {
    double tot = ds[0] + ds[1] + ds[2] + ds[3];
    out_loss[0] = (float)(1.25 * tot / ((double)N_ROWS * (double)DIM));
  }
}

// --------------------------------- launch ----------------------------------

extern "C" void kernel_launch(void* const* d_in, const int* in_sizes, int n_in,
                              void* d_out, int out_size, void* d_ws, size_t ws_size,
                              hipStream_t stream) {
  const float* z_e      = (const float*)d_in[0];
  const float* codebook = (const float*)d_in[1];
  const float* W        = (const float*)d_in[2];
  float* out = (float*)d_out;
  char* ws = (char*)d_ws;

  float*          eff     = (float*)(ws);                 // 33,554,432
  float*          effnorm = (float*)(ws + 33554432);      // 65,536
  _Float16*       WpT     = (_Float16*)(ws + 33619968);   // 1,572,864
  float*          ploss   = (float*)(ws + 36274176);      // 32,768
  // CpT region [36,306,944 .. 86,638,592): dead after effgemm; overlays:
  _Float16*       CpT     = (_Float16*)(ws + 36306944);   // 50,331,648
  float*          gv      = (float*)(ws + 36306944);      // 16,777,216
  _Float16*       ApT     = (_Float16*)(ws + 53084160);   // 8,388,608
  unsigned*       gmask   = (unsigned*)(ws + 61472768);   // 16,777,216 (in hole)
  _Float16*       BpT     = (_Float16*)(ws + 86638592);   // 16,777,216 (to 103,415,808)

  float* out_zq   = out;
  float* out_loss = out + (size_t)N_ROWS * DIM;
  float* out_idx  = out + (size_t)N_ROWS * DIM + 1;

  // 1) 3-limb pre-tiled splits for eff GEMM
  split_tiled_kernel<<<64 * 48, 256, 0, stream>>>(codebook, CpT, 2);
  split_tiled_kernel<<<2 * 48, 256, 0, stream>>>(W, WpT, 1);
  // 2) eff = codebook @ W.T (3-limb f16 MFMA, 128^2 tiles) + fused BpT f16
  effgemm128_kernel<<<512, 256, 0, stream>>>(CpT, WpT, eff, BpT);
  // 3) ||eff_k||^2
  effnorm_kernel<<<K_CB / 4, 256, 0, stream>>>(eff, effnorm);
  // 4) 1-limb pre-tiled split of z (overlays dead CpT region)
  split1_kernel<<<32 * 16, 256, 0, stream>>>(z_e, ApT);
  // 5) approx distance pass + group minima + per-col candidate masks
  dist1_kernel<<<2048, 512, 0, stream>>>(ApT, BpT, effnorm, gv, gmask);
  // 6) fused flag+refine on masked cols + gather z_q + loss partials
  refine_kernel<<<N_ROWS / 4, 256, 0, stream>>>(z_e, eff, effnorm, gv, gmask,
                                                out_zq, out_idx, ploss);
  // 7) final loss
  loss_final_kernel<<<1, 256, 0, stream>>>(ploss, out_loss);
}